// Round 4
// baseline (344.079 us; speedup 1.0000x reference)
//
#include <hip/hip_runtime.h>
#include <hip/hip_bf16.h>

// Static problem shape: B=8, C=256, CQ=8, H=W=128, scale=4, Hd=Wd=32, N=1024

typedef short bf16x8 __attribute__((ext_vector_type(8)));
typedef float f32x4 __attribute__((ext_vector_type(4)));
typedef unsigned short ushort_t;

// fp32 -> bf16 round-to-nearest-even (bit trick)
__device__ __forceinline__ ushort_t f2bf(float f) {
    union { float f; unsigned u; } x{f};
    unsigned r = x.u + 0x7FFF + ((x.u >> 16) & 1);
    return (ushort_t)(r >> 16);
}
__device__ __forceinline__ float bf2f(ushort_t u) {
    return __uint_as_float(((unsigned)u) << 16);
}

#define GLOAD_LDS16(gp, lp)                                                          \
    __builtin_amdgcn_global_load_lds((const __attribute__((address_space(1))) void*)(gp), \
                                     (__attribute__((address_space(3))) void*)(lp), 16, 0, 0)

// ---------------- ws layout (bytes) ----------------
// P    bf16 [8][1024][1024] @ 0         (16 MiB)  -- overlays xf (dead after qk/prep)
// xf   f32  [8][256][1024]  @ 0         (8 MiB, phase 1 only)
// qT   f32  [8][1024][8]    @ 16777216  (256 KB)
// kT   f32  [8][1024][8]    @ 17039360  (256 KB)
// v    bf16 [8][256][1024]  @ 17301504  (4 MiB)
// outs bf16 [8][256][1024]  @ 21495808  (4 MiB)
// xfT  bf16 [8][1024][256]  @ 25690112  (4 MiB)  -- transposed, K(c)-contig
// wvb  bf16 [256][256]      @ 29884416  (128 KB)
// total ~28.6 MiB

// ---------------------------------------------------------------------------
// 1) 4x4 average pool: x[B,C,128,128] -> xf[B,C,1024] (fp32)
__global__ __launch_bounds__(256) void pool_kernel(const float* __restrict__ x,
                                                   float* __restrict__ xf) {
    int idx = blockIdx.x * 256 + threadIdx.x;      // 0..2097151
    int n = idx & 1023;
    int c = (idx >> 10) & 255;
    int b = idx >> 18;
    int hi = n >> 5, wi = n & 31;
    const float* p = x + ((size_t)(b * 256 + c) * 128 + hi * 4) * 128 + wi * 4;
    float s = 0.f;
#pragma unroll
    for (int r = 0; r < 4; ++r) {
        float4 v4 = *(const float4*)(p + r * 128);
        s += v4.x + v4.y + v4.z + v4.w;
    }
    xf[idx] = s * 0.0625f;
}

// ---------------------------------------------------------------------------
// 1b) prep: xfT[b][n][c] = bf16(xf[b][c][n]) (LDS-tiled transpose)  [128 blocks]
//     + wvb = bf16(Wv)                                              [8 blocks]
__global__ __launch_bounds__(256) void prep_kernel(const float* __restrict__ xf,
                                                   const float* __restrict__ Wv,
                                                   ushort_t* __restrict__ xfT,
                                                   ushort_t* __restrict__ wvb) {
    int bid = blockIdx.x;
    int t = threadIdx.x;
    if (bid >= 128) {   // Wv fp32 -> bf16 (65536 elems over 8 blocks)
        int base = (bid - 128) * 8192 + t * 8;
#pragma unroll
        for (int u = 0; u < 8192; u += 2048) {
            float4 a = *(const float4*)(Wv + base + u);
            float4 c4 = *(const float4*)(Wv + base + u + 4);
            bf16x8 r;
            r[0] = (short)f2bf(a.x);  r[1] = (short)f2bf(a.y);
            r[2] = (short)f2bf(a.z);  r[3] = (short)f2bf(a.w);
            r[4] = (short)f2bf(c4.x); r[5] = (short)f2bf(c4.y);
            r[6] = (short)f2bf(c4.z); r[7] = (short)f2bf(c4.w);
            *(bf16x8*)(wvb + base + u) = r;
        }
        return;
    }
    int b = bid >> 4;
    int n0 = (bid & 15) * 64;
    __shared__ float tile[64][68];
    const float* xp = xf + (size_t)b * 262144;
#pragma unroll 1
    for (int c0 = 0; c0 < 256; c0 += 64) {
        {   // stage [64 c][64 n] (coalesced along n)
            int c = t >> 2, nq = (t & 3) * 16;
            const float* p = xp + (size_t)(c0 + c) * 1024 + n0 + nq;
            *(float4*)&tile[c][nq]      = *(const float4*)p;
            *(float4*)&tile[c][nq + 4]  = *(const float4*)(p + 4);
            *(float4*)&tile[c][nq + 8]  = *(const float4*)(p + 8);
            *(float4*)&tile[c][nq + 12] = *(const float4*)(p + 12);
        }
        __syncthreads();
        {   // write transposed bf16 (coalesced along c)
            int n = t >> 2, cq = (t & 3) * 16;
            ushort_t* op = xfT + ((size_t)b * 1024 + n0 + n) * 256 + c0 + cq;
            bf16x8 v0, v1;
#pragma unroll
            for (int u = 0; u < 8; ++u) v0[u] = (short)f2bf(tile[cq + u][n]);
#pragma unroll
            for (int u = 0; u < 8; ++u) v1[u] = (short)f2bf(tile[cq + 8 + u][n]);
            *(bf16x8*)op = v0;
            *(bf16x8*)(op + 8) = v1;
        }
        __syncthreads();
    }
}

// ---------------------------------------------------------------------------
// 2) q,k projections -> qT[B][N][8], kT[B][N][8].
//    grid = 8*32 = 256 blocks; 256 thr = 32 n x 8 c-groups (32 c each).
__global__ __launch_bounds__(256) void qk_kernel(const float* __restrict__ xf,
                                                 const float* __restrict__ Wq,
                                                 const float* __restrict__ bq,
                                                 const float* __restrict__ Wk,
                                                 const float* __restrict__ bk,
                                                 float* __restrict__ qT,
                                                 float* __restrict__ kT) {
    __shared__ float sW[4112];
    __shared__ float red[4352];     // [8 g][32 n][17 pad] -> g*544 + n*17 + j
    int t = threadIdx.x;
    for (int i = t; i < 2048; i += 256) {
        sW[i] = Wq[i];
        sW[2048 + i] = Wk[i];
    }
    if (t < 8) { sW[4096 + t] = bq[t]; sW[4104 + t] = bk[t]; }
    __syncthreads();

    int b = blockIdx.x >> 5;
    int ng = blockIdx.x & 31;
    int nl = t & 31, cg = t >> 5;
    float a[16];
#pragma unroll
    for (int j = 0; j < 16; ++j) a[j] = 0.f;
    const float* xp = xf + (size_t)b * 262144 + ng * 32 + nl;
    for (int c = cg * 32; c < cg * 32 + 32; ++c) {
        float xv = xp[(size_t)c * 1024];
#pragma unroll
        for (int j = 0; j < 8; ++j) {
            a[j]     = fmaf(sW[j * 256 + c], xv, a[j]);
            a[8 + j] = fmaf(sW[2048 + j * 256 + c], xv, a[8 + j]);
        }
    }
    float* rp = &red[cg * 544 + nl * 17];
#pragma unroll
    for (int j = 0; j < 16; ++j) rp[j] = a[j];
    __syncthreads();
#pragma unroll
    for (int u = 0; u < 2; ++u) {
        int o = t * 2 + u;
        int n = o >> 4, j = o & 15;
        float s = sW[4096 + j];
#pragma unroll
        for (int g = 0; g < 8; ++g) s += red[g * 544 + n * 17 + j];
        if (j < 8) qT[((size_t)b * 1024 + ng * 32 + n) * 8 + j] = s;
        else       kT[((size_t)b * 1024 + ng * 32 + n) * 8 + j - 8] = s;
    }
}

// ---------------------------------------------------------------------------
// 3) v projection, bf16 MFMA (pv-structure clone, K=c=256):
//    v[b,o,n] = sum_c wvb[o,c]*xfT[b,n,c] + bv[o]
//    64x64 tile, 2-phase LDS double-buffer (stage next while computing cur).
__global__ __launch_bounds__(256) void vgemm_kernel(const ushort_t* __restrict__ wvb,
                                                    const ushort_t* __restrict__ xfT,
                                                    const float* __restrict__ bv,
                                                    ushort_t* __restrict__ v) {
    int bid = blockIdx.x;
    int b = bid >> 6;
    int ot0 = ((bid >> 4) & 3) * 64;
    int nt0 = (bid & 15) * 64;
    __shared__ __align__(16) short as_[2][4096];   // [64 o][64 c], swizzled cols
    __shared__ __align__(16) short bs_[2][4096];   // [64 n][64 c], swizzled cols
    int t = threadIdx.x;
    int w = t >> 6, ln = t & 63;
    int lrow = ln >> 3, lcol = ln & 7;
    int scol = lcol ^ lrow;                        // inverse-swizzled source col

    const char* ag = (const char*)(wvb + (size_t)ot0 * 256);               // 512B rows
    const char* bg = (const char*)(xfT + ((size_t)b * 1024 + nt0) * 256);  // 512B rows

    f32x4 acc[4] = {};
    int fr = ln & 15, quad = ln >> 4;
    int f7 = fr & 7;

#define VG_STAGE(bb, koff)                                                        \
    {                                                                             \
        _Pragma("unroll")                                                         \
        for (int s = w; s < 8; s += 4) {                                          \
            GLOAD_LDS16(ag + (size_t)(s * 8 + lrow) * 512 + (koff) + scol * 16,   \
                        (char*)as_[bb] + s * 1024);                               \
            GLOAD_LDS16(bg + (size_t)(s * 8 + lrow) * 512 + (koff) + scol * 16,   \
                        (char*)bs_[bb] + s * 1024);                               \
        }                                                                         \
    }

    VG_STAGE(0, 0);
    __syncthreads();
#pragma unroll 1
    for (int it = 0; it < 4; ++it) {
        int cur = it & 1;
        if (it < 3) VG_STAGE(cur ^ 1, (it + 1) * 128);   // issue next-tile loads first
        const char* ab = (const char*)as_[cur] + (w * 16 + fr) * 128;
        const char* bb2 = (const char*)bs_[cur];
#pragma unroll
        for (int kh = 0; kh < 2; ++kh) {
            int cb = ((kh * 4 + quad) ^ f7) * 16;        // swizzled read column
            bf16x8 af = *(const bf16x8*)(ab + cb);
#pragma unroll
            for (int mt = 0; mt < 4; ++mt) {
                bf16x8 bfr = *(const bf16x8*)(bb2 + (mt * 16 + fr) * 128 + cb);
                acc[mt] = __builtin_amdgcn_mfma_f32_16x16x32_bf16(af, bfr, acc[mt], 0, 0, 0);
            }
        }
        __syncthreads();   // drains vmcnt(0): next tile resident; cur reads done
    }
#undef VG_STAGE
    // epilogue: row (quad*4+r) = o, col (mt*16+fr) = n
    ushort_t* og = v + (size_t)(b * 256 + ot0 + w * 16) * 1024 + nt0;
#pragma unroll
    for (int mt = 0; mt < 4; ++mt) {
#pragma unroll
        for (int r = 0; r < 4; ++r) {
            int o = quad * 4 + r;
            float bias = bv[ot0 + w * 16 + o];
            og[(size_t)o * 1024 + mt * 16 + fr] = f2bf(acc[mt][r] + bias);
        }
    }
}

// ---------------------------------------------------------------------------
// 4) fused softmax stats + P matrix (bf16): P[b,m,n] = exp(q_m.k_n - M_m)/L_m
//    k stored as two contiguous float4 planes (conflict-free ds_read_b128).
__global__ __launch_bounds__(256) void pmat_kernel(const float* __restrict__ qT,
                                                   const float* __restrict__ kT,
                                                   ushort_t* __restrict__ Pm) {
    __shared__ float4 kst[2048];   // [h][n]: h=0 -> k[0..3], h=1 -> k[4..7]
    int t = threadIdx.x;
    int b = blockIdx.x >> 6;
    int mg = blockIdx.x & 63;
    const float* kp = kT + (size_t)b * 8192;
    for (int i4 = t * 4; i4 < 8192; i4 += 1024) {
        float4 kv = *(const float4*)&kp[i4];
        int n = i4 >> 3;
        int h = (i4 >> 2) & 1;
        kst[h * 1024 + n] = kv;
    }
    __syncthreads();

    int w = t >> 6, ln = t & 63;
#pragma unroll 1
    for (int pass = 0; pass < 4; ++pass) {
        int m = mg * 16 + pass * 4 + w;
        const float* qp = qT + ((size_t)b * 1024 + m) * 8;
        float4 q0 = *(const float4*)qp, q1 = *(const float4*)(qp + 4);
        float s[16];
        float mx = -1e30f;
#pragma unroll
        for (int i = 0; i < 16; ++i) {
            float4 k0 = kst[ln + i * 64];
            float4 k1 = kst[1024 + ln + i * 64];
            float d = q0.x * k0.x + q0.y * k0.y + q0.z * k0.z + q0.w * k0.w +
                      q1.x * k1.x + q1.y * k1.y + q1.z * k1.z + q1.w * k1.w;
            s[i] = d;
            mx = fmaxf(mx, d);
        }
#pragma unroll
        for (int off = 32; off; off >>= 1) mx = fmaxf(mx, __shfl_xor(mx, off, 64));
        float sum = 0.f;
#pragma unroll
        for (int i = 0; i < 16; ++i) { s[i] = __expf(s[i] - mx); sum += s[i]; }
#pragma unroll
        for (int off = 32; off; off >>= 1) sum += __shfl_xor(sum, off, 64);
        float inv = 1.0f / sum;
        ushort_t* pp = Pm + ((size_t)b * 1024 + m) * 1024;
#pragma unroll
        for (int i = 0; i < 16; ++i) pp[ln + i * 64] = f2bf(s[i] * inv);
    }
}

// ---------------------------------------------------------------------------
// 5) PV GEMM, bf16 MFMA: outs[b,c,m] = sum_n v[b,c,n] * P[b,m,n]
//    64x64 tile, XOR-swizzled LDS, 2-phase double-buffer (T3 minimum):
//    issue next tile's global_load_lds BEFORE computing current tile so the
//    ~600cy load latency overlaps the MFMA phase instead of a dead drain.
__global__ __launch_bounds__(256) void pv_mfma_kernel(const ushort_t* __restrict__ v,
                                                      const ushort_t* __restrict__ Pm,
                                                      ushort_t* __restrict__ outs) {
    int bid = blockIdx.x;
    int b = bid >> 6;
    int ct0 = ((bid >> 4) & 3) * 64;
    int mt0 = (bid & 15) * 64;
    __shared__ __align__(16) short vs[2][4096];   // [64 c][64 k] bf16, swizzled cols
    __shared__ __align__(16) short ps[2][4096];   // [64 m][64 k] bf16, swizzled cols
    int t = threadIdx.x;
    int w = t >> 6, ln = t & 63;
    int lrow = ln >> 3, lcol = ln & 7;
    int scol = lcol ^ lrow;

    const char* vg = (const char*)(v + (size_t)(b * 256 + ct0) * 1024);
    const char* pg = (const char*)(Pm + (size_t)(b * 1024 + mt0) * 1024);

    f32x4 acc[4] = {};
    int fr = ln & 15, quad = ln >> 4;
    int f7 = fr & 7;

#define PV_STAGE(bb, koff)                                                        \
    {                                                                             \
        _Pragma("unroll")                                                         \
        for (int s = w; s < 8; s += 4) {                                          \
            GLOAD_LDS16(vg + (size_t)(s * 8 + lrow) * 2048 + (koff) + scol * 16,  \
                        (char*)vs[bb] + s * 1024);                                \
            GLOAD_LDS16(pg + (size_t)(s * 8 + lrow) * 2048 + (koff) + scol * 16,  \
                        (char*)ps[bb] + s * 1024);                                \
        }                                                                         \
    }

    PV_STAGE(0, 0);
    __syncthreads();
#pragma unroll 1
    for (int it = 0; it < 16; ++it) {
        int cur = it & 1;
        if (it < 15) PV_STAGE(cur ^ 1, (it + 1) * 128);   // prefetch next K-tile
        const char* vb = (const char*)vs[cur] + (w * 16 + fr) * 128;
        const char* pb = (const char*)ps[cur];
#pragma unroll
        for (int kh = 0; kh < 2; ++kh) {
            int cb = ((kh * 4 + quad) ^ f7) * 16;    // swizzled read column
            bf16x8 af = *(const bf16x8*)(vb + cb);
#pragma unroll
            for (int mt = 0; mt < 4; ++mt) {
                bf16x8 bfr = *(const bf16x8*)(pb + (mt * 16 + fr) * 128 + cb);
                acc[mt] = __builtin_amdgcn_mfma_f32_16x16x32_bf16(af, bfr, acc[mt], 0, 0, 0);
            }
        }
        __syncthreads();   // drains vmcnt(0): prefetched tile resident
    }
#undef PV_STAGE
    // epilogue: C/D layout col=lane&15 (m), row=quad*4+reg (c)
    ushort_t* og = outs + (size_t)(b * 256 + ct0 + w * 16) * 1024 + mt0;
#pragma unroll
    for (int mt = 0; mt < 4; ++mt) {
#pragma unroll
        for (int r = 0; r < 4; ++r) {
            int c = quad * 4 + r;
            og[(size_t)c * 1024 + mt * 16 + fr] = f2bf(acc[mt][r]);
        }
    }
}

// ---------------------------------------------------------------------------
// 6) bilinear 4x upsample + residual: out = gamma*up(outs) + x
__global__ __launch_bounds__(256) void up_kernel(const ushort_t* __restrict__ outs,
                                                 const float* __restrict__ x,
                                                 const float* __restrict__ gamma,
                                                 float* __restrict__ out) {
    int bc = blockIdx.x;   // 0..2047
    __shared__ float P[32][33];
    __shared__ float R[128][33];   // R[h][w'] = (1-fh)*P[ha][w'] + fh*P[hb][w']
    int t = threadIdx.x;
    const ushort_t* sp = outs + (size_t)bc * 1024;
    for (int i = t; i < 1024; i += 256) P[i >> 5][i & 31] = bf2f(sp[i]);
    float g = gamma[0];
    __syncthreads();

    {   // vertical interpolation: 128 h x 32 w' = 16 values/thread
        int wq = t & 31;
        int hbase = (t >> 5) * 16;
#pragma unroll
        for (int hh = 0; hh < 16; ++hh) {
            int h = hbase + hh;
            int hq = h >> 2, r = h & 3;
            int i0 = hq + ((r < 2) ? -1 : 0);
            float fh = (r < 2) ? (0.625f + 0.25f * r) : (0.25f * r - 0.375f);
            int ha = i0 < 0 ? 0 : i0;
            int hb = (i0 + 1) > 31 ? 31 : (i0 + 1);
            R[h][wq] = (1.f - fh) * P[ha][wq] + fh * P[hb][wq];
        }
    }
    __syncthreads();

    const float* xp = x + (size_t)bc * 16384;
    float* op = out + (size_t)bc * 16384;
#pragma unroll 1
    for (int it = 0; it < 16; ++it) {
        int pix = it * 256 + t;        // float4 index 0..4095
        int h = pix >> 5;
        int wq = pix & 31;
        float4 xv = *(const float4*)(xp + h * 128 + wq * 4);
        float res[4];
#pragma unroll
        for (int k = 0; k < 4; ++k) {
            int j0 = wq + ((k < 2) ? -1 : 0);
            float fw = (k < 2) ? (0.625f + 0.25f * k) : (0.25f * k - 0.375f);
            int wa = j0 < 0 ? 0 : j0;
            int wb = (j0 + 1) > 31 ? 31 : (j0 + 1);
            res[k] = (1.f - fw) * R[h][wa] + fw * R[h][wb];
        }
        f32x4 o;
        o[0] = fmaf(g, res[0], xv.x);
        o[1] = fmaf(g, res[1], xv.y);
        o[2] = fmaf(g, res[2], xv.z);
        o[3] = fmaf(g, res[3], xv.w);
        __builtin_nontemporal_store(o, (f32x4*)(op + h * 128 + wq * 4));
    }
}

// ---------------------------------------------------------------------------
extern "C" void kernel_launch(void* const* d_in, const int* in_sizes, int n_in,
                              void* d_out, int out_size, void* d_ws, size_t ws_size,
                              hipStream_t stream) {
    const float* x     = (const float*)d_in[0];
    const float* Wq    = (const float*)d_in[1];
    const float* bq    = (const float*)d_in[2];
    const float* Wk    = (const float*)d_in[3];
    const float* bk    = (const float*)d_in[4];
    const float* Wv    = (const float*)d_in[5];
    const float* bv    = (const float*)d_in[6];
    const float* gamma = (const float*)d_in[7];
    float* out = (float*)d_out;

    char* wsb = (char*)d_ws;
    float*    xf   = (float*)wsb;                    // 8 MiB (dead after qk/prep)
    ushort_t* Pmat = (ushort_t*)wsb;                 // 16 MiB (overlays xf)
    float*    qT   = (float*)(wsb + 16777216);
    float*    kT   = (float*)(wsb + 17039360);
    ushort_t* v    = (ushort_t*)(wsb + 17301504);
    ushort_t* outs = (ushort_t*)(wsb + 21495808);
    ushort_t* xfT  = (ushort_t*)(wsb + 25690112);
    ushort_t* wvb  = (ushort_t*)(wsb + 29884416);

    pool_kernel<<<8192, 256, 0, stream>>>(x, xf);
    prep_kernel<<<136, 256, 0, stream>>>(xf, Wv, xfT, wvb);
    qk_kernel<<<256, 256, 0, stream>>>(xf, Wq, bq, Wk, bk, qT, kT);
    vgemm_kernel<<<512, 256, 0, stream>>>(wvb, xfT, bv, v);
    pmat_kernel<<<512, 256, 0, stream>>>(qT, kT, Pmat);
    pv_mfma_kernel<<<512, 256, 0, stream>>>(v, Pmat, outs);
    up_kernel<<<2048, 256, 0, stream>>>(outs, x, gamma, out);
}

// Round 5
// 305.005 us; speedup vs baseline: 1.1281x; 1.1281x over previous
//
#include <hip/hip_runtime.h>
#include <hip/hip_bf16.h>

// Static problem shape: B=8, C=256, CQ=8, H=W=128, scale=4, Hd=Wd=32, N=1024

typedef short bf16x8 __attribute__((ext_vector_type(8)));
typedef float f32x4 __attribute__((ext_vector_type(4)));
typedef unsigned short ushort_t;

// fp32 -> bf16 round-to-nearest-even (bit trick)
__device__ __forceinline__ ushort_t f2bf(float f) {
    union { float f; unsigned u; } x{f};
    unsigned r = x.u + 0x7FFF + ((x.u >> 16) & 1);
    return (ushort_t)(r >> 16);
}
__device__ __forceinline__ float bf2f(ushort_t u) {
    return __uint_as_float(((unsigned)u) << 16);
}

#define GLOAD_LDS16(gp, lp)                                                          \
    __builtin_amdgcn_global_load_lds((const __attribute__((address_space(1))) void*)(gp), \
                                     (__attribute__((address_space(3))) void*)(lp), 16, 0, 0)

// ---------------- ws layout (bytes) ----------------
// P    bf16 [8][1024][1024] @ 0         (16 MiB)  -- overlays xf (dead after qk/prep)
// xf   f32  [8][256][1024]  @ 0         (8 MiB, phase 1 only)
// qT   f32  [8][1024][8]    @ 16777216  (256 KB)
// kT   f32  [8][1024][8]    @ 17039360  (256 KB)
// v    bf16 [8][256][1024]  @ 17301504  (4 MiB)
// outs bf16 [8][256][1024]  @ 21495808  (4 MiB)
// xfT  bf16 [8][1024][256]  @ 25690112  (4 MiB)  -- transposed, K(c)-contig
// wvb  bf16 [256][256]      @ 29884416  (128 KB)
// total ~28.6 MiB

// ---------------------------------------------------------------------------
// 1) 4x4 average pool: x[B,C,128,128] -> xf[B,C,1024] (fp32)
__global__ __launch_bounds__(256) void pool_kernel(const float* __restrict__ x,
                                                   float* __restrict__ xf) {
    int idx = blockIdx.x * 256 + threadIdx.x;      // 0..2097151
    int n = idx & 1023;
    int c = (idx >> 10) & 255;
    int b = idx >> 18;
    int hi = n >> 5, wi = n & 31;
    const float* p = x + ((size_t)(b * 256 + c) * 128 + hi * 4) * 128 + wi * 4;
    float s = 0.f;
#pragma unroll
    for (int r = 0; r < 4; ++r) {
        float4 v4 = *(const float4*)(p + r * 128);
        s += v4.x + v4.y + v4.z + v4.w;
    }
    xf[idx] = s * 0.0625f;
}

// ---------------------------------------------------------------------------
// 1b) prep: xfT[b][n][c] = bf16(xf[b][c][n]) (LDS-tiled transpose)  [256 blocks]
//     + wvb = bf16(Wv)                                              [8 blocks]
//     32-n tiles -> 1 block/CU (was 1/2); pad 37 (5*8 mod 32 = 8) makes the
//     transposed column-read 2-way bank aliasing (free) instead of 8-way.
__global__ __launch_bounds__(256) void prep_kernel(const float* __restrict__ xf,
                                                   const float* __restrict__ Wv,
                                                   ushort_t* __restrict__ xfT,
                                                   ushort_t* __restrict__ wvb) {
    int bid = blockIdx.x;
    int t = threadIdx.x;
    if (bid >= 256) {   // Wv fp32 -> bf16 (65536 elems over 8 blocks)
        int base = (bid - 256) * 8192 + t * 8;
#pragma unroll
        for (int u = 0; u < 8192; u += 2048) {
            float4 a = *(const float4*)(Wv + base + u);
            float4 c4 = *(const float4*)(Wv + base + u + 4);
            bf16x8 r;
            r[0] = (short)f2bf(a.x);  r[1] = (short)f2bf(a.y);
            r[2] = (short)f2bf(a.z);  r[3] = (short)f2bf(a.w);
            r[4] = (short)f2bf(c4.x); r[5] = (short)f2bf(c4.y);
            r[6] = (short)f2bf(c4.z); r[7] = (short)f2bf(c4.w);
            *(bf16x8*)(wvb + base + u) = r;
        }
        return;
    }
    int b = bid >> 5;
    int n0 = (bid & 31) * 32;
    __shared__ float tile[64][37];
    const float* xp = xf + (size_t)b * 262144;
#pragma unroll 1
    for (int c0 = 0; c0 < 256; c0 += 64) {
        {   // stage [64 c][32 n] (coalesced along n)
            int c = t >> 2, nq = (t & 3) * 8;
            const float* p = xp + (size_t)(c0 + c) * 1024 + n0 + nq;
            *(float4*)&tile[c][nq]     = *(const float4*)p;
            *(float4*)&tile[c][nq + 4] = *(const float4*)(p + 4);
        }
        __syncthreads();
        {   // write transposed bf16 (coalesced along c)
            int n = t >> 3, cq = (t & 7) * 8;
            ushort_t* op = xfT + ((size_t)b * 1024 + n0 + n) * 256 + c0 + cq;
            bf16x8 v0;
#pragma unroll
            for (int u = 0; u < 8; ++u) v0[u] = (short)f2bf(tile[cq + u][n]);
            *(bf16x8*)op = v0;
        }
        __syncthreads();
    }
}

// ---------------------------------------------------------------------------
// 2) q,k projections -> qT[B][N][8], kT[B][N][8].
//    grid = 8*64 = 512 blocks; 256 thr = 16 n x 16 c-groups (16 c each).
//    2 blocks/CU; serial c-chain 16 iters.
__global__ __launch_bounds__(256) void qk_kernel(const float* __restrict__ xf,
                                                 const float* __restrict__ Wq,
                                                 const float* __restrict__ bq,
                                                 const float* __restrict__ Wk,
                                                 const float* __restrict__ bk,
                                                 float* __restrict__ qT,
                                                 float* __restrict__ kT) {
    __shared__ float sW[4112];
    __shared__ float red[4352];     // [16 g][16 n][17 pad] -> g*272 + n*17 + j
    int t = threadIdx.x;
    for (int i = t; i < 2048; i += 256) {
        sW[i] = Wq[i];
        sW[2048 + i] = Wk[i];
    }
    if (t < 8) { sW[4096 + t] = bq[t]; sW[4104 + t] = bk[t]; }
    __syncthreads();

    int b = blockIdx.x >> 6;
    int ng = blockIdx.x & 63;
    int nl = t & 15, cg = t >> 4;
    float a[16];
#pragma unroll
    for (int j = 0; j < 16; ++j) a[j] = 0.f;
    const float* xp = xf + (size_t)b * 262144 + ng * 16 + nl;
    for (int c = cg * 16; c < cg * 16 + 16; ++c) {
        float xv = xp[(size_t)c * 1024];
#pragma unroll
        for (int j = 0; j < 8; ++j) {
            a[j]     = fmaf(sW[j * 256 + c], xv, a[j]);
            a[8 + j] = fmaf(sW[2048 + j * 256 + c], xv, a[8 + j]);
        }
    }
    float* rp = &red[cg * 272 + nl * 17];
#pragma unroll
    for (int j = 0; j < 16; ++j) rp[j] = a[j];
    __syncthreads();
    {
        int n = t >> 4, j = t & 15;
        float s = sW[4096 + j];
#pragma unroll
        for (int g = 0; g < 16; ++g) s += red[g * 272 + n * 17 + j];
        if (j < 8) qT[((size_t)b * 1024 + ng * 16 + n) * 8 + j] = s;
        else       kT[((size_t)b * 1024 + ng * 16 + n) * 8 + j - 8] = s;
    }
}

// ---------------------------------------------------------------------------
// 3) v projection, bf16 MFMA (pv-structure clone, K=c=256):
//    v[b,o,n] = sum_c wvb[o,c]*xfT[b,n,c] + bv[o]
//    64x64 tile, 2-phase LDS double-buffer (stage next while computing cur).
__global__ __launch_bounds__(256) void vgemm_kernel(const ushort_t* __restrict__ wvb,
                                                    const ushort_t* __restrict__ xfT,
                                                    const float* __restrict__ bv,
                                                    ushort_t* __restrict__ v) {
    int bid = blockIdx.x;
    int b = bid >> 6;
    int ot0 = ((bid >> 4) & 3) * 64;
    int nt0 = (bid & 15) * 64;
    __shared__ __align__(16) short as_[2][4096];   // [64 o][64 c], swizzled cols
    __shared__ __align__(16) short bs_[2][4096];   // [64 n][64 c], swizzled cols
    int t = threadIdx.x;
    int w = t >> 6, ln = t & 63;
    int lrow = ln >> 3, lcol = ln & 7;
    int scol = lcol ^ lrow;                        // inverse-swizzled source col

    const char* ag = (const char*)(wvb + (size_t)ot0 * 256);               // 512B rows
    const char* bg = (const char*)(xfT + ((size_t)b * 1024 + nt0) * 256);  // 512B rows

    f32x4 acc[4] = {};
    int fr = ln & 15, quad = ln >> 4;
    int f7 = fr & 7;

#define VG_STAGE(bb, koff)                                                        \
    {                                                                             \
        _Pragma("unroll")                                                         \
        for (int s = w; s < 8; s += 4) {                                          \
            GLOAD_LDS16(ag + (size_t)(s * 8 + lrow) * 512 + (koff) + scol * 16,   \
                        (char*)as_[bb] + s * 1024);                               \
            GLOAD_LDS16(bg + (size_t)(s * 8 + lrow) * 512 + (koff) + scol * 16,   \
                        (char*)bs_[bb] + s * 1024);                               \
        }                                                                         \
    }

    VG_STAGE(0, 0);
    __syncthreads();
#pragma unroll 1
    for (int it = 0; it < 4; ++it) {
        int cur = it & 1;
        if (it < 3) VG_STAGE(cur ^ 1, (it + 1) * 128);   // issue next-tile loads first
        const char* ab = (const char*)as_[cur] + (w * 16 + fr) * 128;
        const char* bb2 = (const char*)bs_[cur];
#pragma unroll
        for (int kh = 0; kh < 2; ++kh) {
            int cb = ((kh * 4 + quad) ^ f7) * 16;        // swizzled read column
            bf16x8 af = *(const bf16x8*)(ab + cb);
#pragma unroll
            for (int mt = 0; mt < 4; ++mt) {
                bf16x8 bfr = *(const bf16x8*)(bb2 + (mt * 16 + fr) * 128 + cb);
                acc[mt] = __builtin_amdgcn_mfma_f32_16x16x32_bf16(af, bfr, acc[mt], 0, 0, 0);
            }
        }
        __syncthreads();   // drains vmcnt(0): next tile resident; cur reads done
    }
#undef VG_STAGE
    // epilogue: row (quad*4+r) = o, col (mt*16+fr) = n
    ushort_t* og = v + (size_t)(b * 256 + ot0 + w * 16) * 1024 + nt0;
#pragma unroll
    for (int mt = 0; mt < 4; ++mt) {
#pragma unroll
        for (int r = 0; r < 4; ++r) {
            int o = quad * 4 + r;
            float bias = bv[ot0 + w * 16 + o];
            og[(size_t)o * 1024 + mt * 16 + fr] = f2bf(acc[mt][r] + bias);
        }
    }
}

// ---------------------------------------------------------------------------
// 4) fused softmax stats + P matrix (bf16): P[b,m,n] = exp(q_m.k_n - M_m)/L_m
//    grid = 8*128 = 1024 blocks (4 blocks/CU); block handles 8 m rows.
//    k stored as two contiguous float4 planes (conflict-free ds_read_b128).
__global__ __launch_bounds__(256) void pmat_kernel(const float* __restrict__ qT,
                                                   const float* __restrict__ kT,
                                                   ushort_t* __restrict__ Pm) {
    __shared__ float4 kst[2048];   // [h][n]: h=0 -> k[0..3], h=1 -> k[4..7]
    int t = threadIdx.x;
    int b = blockIdx.x >> 7;
    int mg = blockIdx.x & 127;
    const float* kp = kT + (size_t)b * 8192;
    for (int i4 = t * 4; i4 < 8192; i4 += 1024) {
        float4 kv = *(const float4*)&kp[i4];
        int n = i4 >> 3;
        int h = (i4 >> 2) & 1;
        kst[h * 1024 + n] = kv;
    }
    __syncthreads();

    int w = t >> 6, ln = t & 63;
#pragma unroll 1
    for (int pass = 0; pass < 2; ++pass) {
        int m = mg * 8 + pass * 4 + w;
        const float* qp = qT + ((size_t)b * 1024 + m) * 8;
        float4 q0 = *(const float4*)qp, q1 = *(const float4*)(qp + 4);
        float s[16];
        float mx = -1e30f;
#pragma unroll
        for (int i = 0; i < 16; ++i) {
            float4 k0 = kst[ln + i * 64];
            float4 k1 = kst[1024 + ln + i * 64];
            float d = q0.x * k0.x + q0.y * k0.y + q0.z * k0.z + q0.w * k0.w +
                      q1.x * k1.x + q1.y * k1.y + q1.z * k1.z + q1.w * k1.w;
            s[i] = d;
            mx = fmaxf(mx, d);
        }
#pragma unroll
        for (int off = 32; off; off >>= 1) mx = fmaxf(mx, __shfl_xor(mx, off, 64));
        float sum = 0.f;
#pragma unroll
        for (int i = 0; i < 16; ++i) { s[i] = __expf(s[i] - mx); sum += s[i]; }
#pragma unroll
        for (int off = 32; off; off >>= 1) sum += __shfl_xor(sum, off, 64);
        float inv = 1.0f / sum;
        ushort_t* pp = Pm + ((size_t)b * 1024 + m) * 1024;
#pragma unroll
        for (int i = 0; i < 16; ++i) pp[ln + i * 64] = f2bf(s[i] * inv);
    }
}

// ---------------------------------------------------------------------------
// 5) PV GEMM, bf16 MFMA: outs[b,c,m] = sum_n v[b,c,n] * P[b,m,n]
//    64x64 tile, XOR-swizzled LDS, 2-phase double-buffer (T3 minimum):
//    issue next tile's global_load_lds BEFORE computing current tile so the
//    load latency overlaps the MFMA phase instead of a dead drain.
__global__ __launch_bounds__(256) void pv_mfma_kernel(const ushort_t* __restrict__ v,
                                                      const ushort_t* __restrict__ Pm,
                                                      ushort_t* __restrict__ outs) {
    int bid = blockIdx.x;
    int b = bid >> 6;
    int ct0 = ((bid >> 4) & 3) * 64;
    int mt0 = (bid & 15) * 64;
    __shared__ __align__(16) short vs[2][4096];   // [64 c][64 k] bf16, swizzled cols
    __shared__ __align__(16) short ps[2][4096];   // [64 m][64 k] bf16, swizzled cols
    int t = threadIdx.x;
    int w = t >> 6, ln = t & 63;
    int lrow = ln >> 3, lcol = ln & 7;
    int scol = lcol ^ lrow;

    const char* vg = (const char*)(v + (size_t)(b * 256 + ct0) * 1024);
    const char* pg = (const char*)(Pm + (size_t)(b * 1024 + mt0) * 1024);

    f32x4 acc[4] = {};
    int fr = ln & 15, quad = ln >> 4;
    int f7 = fr & 7;

#define PV_STAGE(bb, koff)                                                        \
    {                                                                             \
        _Pragma("unroll")                                                         \
        for (int s = w; s < 8; s += 4) {                                          \
            GLOAD_LDS16(vg + (size_t)(s * 8 + lrow) * 2048 + (koff) + scol * 16,  \
                        (char*)vs[bb] + s * 1024);                                \
            GLOAD_LDS16(pg + (size_t)(s * 8 + lrow) * 2048 + (koff) + scol * 16,  \
                        (char*)ps[bb] + s * 1024);                                \
        }                                                                         \
    }

    PV_STAGE(0, 0);
    __syncthreads();
#pragma unroll 1
    for (int it = 0; it < 16; ++it) {
        int cur = it & 1;
        if (it < 15) PV_STAGE(cur ^ 1, (it + 1) * 128);   // prefetch next K-tile
        const char* vb = (const char*)vs[cur] + (w * 16 + fr) * 128;
        const char* pb = (const char*)ps[cur];
#pragma unroll
        for (int kh = 0; kh < 2; ++kh) {
            int cb = ((kh * 4 + quad) ^ f7) * 16;    // swizzled read column
            bf16x8 af = *(const bf16x8*)(vb + cb);
#pragma unroll
            for (int mt = 0; mt < 4; ++mt) {
                bf16x8 bfr = *(const bf16x8*)(pb + (mt * 16 + fr) * 128 + cb);
                acc[mt] = __builtin_amdgcn_mfma_f32_16x16x32_bf16(af, bfr, acc[mt], 0, 0, 0);
            }
        }
        __syncthreads();   // drains vmcnt(0): prefetched tile resident
    }
#undef PV_STAGE
    // epilogue: C/D layout col=lane&15 (m), row=quad*4+reg (c)
    ushort_t* og = outs + (size_t)(b * 256 + ct0 + w * 16) * 1024 + mt0;
#pragma unroll
    for (int mt = 0; mt < 4; ++mt) {
#pragma unroll
        for (int r = 0; r < 4; ++r) {
            int c = quad * 4 + r;
            og[(size_t)c * 1024 + mt * 16 + fr] = f2bf(acc[mt][r]);
        }
    }
}

// ---------------------------------------------------------------------------
// 6) bilinear 4x upsample + residual: out = gamma*up(outs) + x
__global__ __launch_bounds__(256) void up_kernel(const ushort_t* __restrict__ outs,
                                                 const float* __restrict__ x,
                                                 const float* __restrict__ gamma,
                                                 float* __restrict__ out) {
    int bc = blockIdx.x;   // 0..2047
    __shared__ float P[32][33];
    __shared__ float R[128][33];   // R[h][w'] = (1-fh)*P[ha][w'] + fh*P[hb][w']
    int t = threadIdx.x;
    const ushort_t* sp = outs + (size_t)bc * 1024;
    for (int i = t; i < 1024; i += 256) P[i >> 5][i & 31] = bf2f(sp[i]);
    float g = gamma[0];
    __syncthreads();

    {   // vertical interpolation: 128 h x 32 w' = 16 values/thread
        int wq = t & 31;
        int hbase = (t >> 5) * 16;
#pragma unroll
        for (int hh = 0; hh < 16; ++hh) {
            int h = hbase + hh;
            int hq = h >> 2, r = h & 3;
            int i0 = hq + ((r < 2) ? -1 : 0);
            float fh = (r < 2) ? (0.625f + 0.25f * r) : (0.25f * r - 0.375f);
            int ha = i0 < 0 ? 0 : i0;
            int hb = (i0 + 1) > 31 ? 31 : (i0 + 1);
            R[h][wq] = (1.f - fh) * P[ha][wq] + fh * P[hb][wq];
        }
    }
    __syncthreads();

    const float* xp = x + (size_t)bc * 16384;
    float* op = out + (size_t)bc * 16384;
#pragma unroll 1
    for (int it = 0; it < 16; ++it) {
        int pix = it * 256 + t;        // float4 index 0..4095
        int h = pix >> 5;
        int wq = pix & 31;
        float4 xv = *(const float4*)(xp + h * 128 + wq * 4);
        float res[4];
#pragma unroll
        for (int k = 0; k < 4; ++k) {
            int j0 = wq + ((k < 2) ? -1 : 0);
            float fw = (k < 2) ? (0.625f + 0.25f * k) : (0.25f * k - 0.375f);
            int wa = j0 < 0 ? 0 : j0;
            int wb = (j0 + 1) > 31 ? 31 : (j0 + 1);
            res[k] = (1.f - fw) * R[h][wa] + fw * R[h][wb];
        }
        f32x4 o;
        o[0] = fmaf(g, res[0], xv.x);
        o[1] = fmaf(g, res[1], xv.y);
        o[2] = fmaf(g, res[2], xv.z);
        o[3] = fmaf(g, res[3], xv.w);
        __builtin_nontemporal_store(o, (f32x4*)(op + h * 128 + wq * 4));
    }
}

// ---------------------------------------------------------------------------
extern "C" void kernel_launch(void* const* d_in, const int* in_sizes, int n_in,
                              void* d_out, int out_size, void* d_ws, size_t ws_size,
                              hipStream_t stream) {
    const float* x     = (const float*)d_in[0];
    const float* Wq    = (const float*)d_in[1];
    const float* bq    = (const float*)d_in[2];
    const float* Wk    = (const float*)d_in[3];
    const float* bk    = (const float*)d_in[4];
    const float* Wv    = (const float*)d_in[5];
    const float* bv    = (const float*)d_in[6];
    const float* gamma = (const float*)d_in[7];
    float* out = (float*)d_out;

    char* wsb = (char*)d_ws;
    float*    xf   = (float*)wsb;                    // 8 MiB (dead after qk/prep)
    ushort_t* Pmat = (ushort_t*)wsb;                 // 16 MiB (overlays xf)
    float*    qT   = (float*)(wsb + 16777216);
    float*    kT   = (float*)(wsb + 17039360);
    ushort_t* v    = (ushort_t*)(wsb + 17301504);
    ushort_t* outs = (ushort_t*)(wsb + 21495808);
    ushort_t* xfT  = (ushort_t*)(wsb + 25690112);
    ushort_t* wvb  = (ushort_t*)(wsb + 29884416);

    pool_kernel<<<8192, 256, 0, stream>>>(x, xf);
    prep_kernel<<<264, 256, 0, stream>>>(xf, Wv, xfT, wvb);
    qk_kernel<<<512, 256, 0, stream>>>(xf, Wq, bq, Wk, bk, qT, kT);
    vgemm_kernel<<<512, 256, 0, stream>>>(wvb, xfT, bv, v);
    pmat_kernel<<<1024, 256, 0, stream>>>(qT, kT, Pmat);
    pv_mfma_kernel<<<512, 256, 0, stream>>>(v, Pmat, outs);
    up_kernel<<<2048, 256, 0, stream>>>(outs, x, gamma, out);
}